// Round 1
// baseline (773.099 us; speedup 1.0000x reference)
//
#include <hip/hip_runtime.h>
#include <math.h>

#define ZD 64
#define YD 32
#define XD 64
#define NCH 32
#define ZYX (ZD*YD*XD)
#define YX (YD*XD)
#define NB 4
#define NTILE 128   // (64/4) z-tiles * (32/4) y-tiles
#define INVC (1.0f/(32.0f+1e-6f))
#define D2R 0.017453292519943295f
#define R2D 57.29577951308232f

// ---------------------------------------------------------------------------
// Kernel 1: fused (rotate-warp feat1) x (27-offset correlation vs feat0),
// reduced over space -> partial[n][tile][27].
// Thread owns 4 x-consecutive positions; featN sampled bilinearly (fy==0).
// ---------------------------------------------------------------------------
__global__ __launch_bounds__(256) void k_heat(const float* __restrict__ feat0,
                                              const float* __restrict__ feat1,
                                              float* __restrict__ partial)
{
    const int n = blockIdx.y;            // 0..11  (b*3 + r)
    const int tile = blockIdx.x;         // 0..127
    const int b = n / 3, r = n % 3;
    const int tid = (int)threadIdx.x;
    const int tx  = tid & 15;            // x-group: x0 = 4*tx
    const int tyy = (tid >> 4) & 3;
    const int tzz = tid >> 6;            // wave-uniform z
    const int z = (tile >> 3) * 4 + tzz;
    const int y = (tile & 7) * 4 + tyy;
    const int x0 = tx << 2;

    const float th = (-4.0f + 4.0f * (float)r) * D2R;
    const float cs = cosf(th), sn = sinf(th);

    // Bilinear (x,z) corner setup for the 4 owned positions
    int   cidx[4][4];
    float cw[4][4];
    const float rzc = (float)z - 31.5f;
    #pragma unroll
    for (int i = 0; i < 4; ++i) {
        float rx = (float)(x0 + i) - 31.5f;
        float sx = cs * rx - sn * rzc + 31.5f;
        float sz = sn * rx + cs * rzc + 31.5f;
        float xf = floorf(sx), zf = floorf(sz);
        float fx = sx - xf, fz = sz - zf;
        int ix = (int)xf, iz = (int)zf;
        bool vx0 = (unsigned)ix < 64u, vx1 = (unsigned)(ix + 1) < 64u;
        bool vz0 = (unsigned)iz < 64u, vz1 = (unsigned)(iz + 1) < 64u;
        int cx0 = min(max(ix, 0), 63), cx1 = min(max(ix + 1, 0), 63);
        int cz0 = min(max(iz, 0), 63), cz1 = min(max(iz + 1, 0), 63);
        cw[i][0] = (vx0 && vz0) ? (1.0f - fx) * (1.0f - fz) : 0.0f;
        cw[i][1] = (vx1 && vz0) ? fx * (1.0f - fz) : 0.0f;
        cw[i][2] = (vx0 && vz1) ? (1.0f - fx) * fz : 0.0f;
        cw[i][3] = (vx1 && vz1) ? fx * fz : 0.0f;
        const int rowy = y * XD;
        cidx[i][0] = cz0 * YX + rowy + cx0;
        cidx[i][1] = cz0 * YX + rowy + cx1;
        cidx[i][2] = cz1 * YX + rowy + cx0;
        cidx[i][3] = cz1 * YX + rowy + cx1;
    }

    float acc[27];
    #pragma unroll
    for (int o = 0; o < 27; ++o) acc[o] = 0.0f;

    const float* f1b = feat1 + (size_t)b * NCH * ZYX;
    const float* f0b = feat0 + (size_t)b * NCH * ZYX;

    #pragma unroll 1
    for (int c0 = 0; c0 < NCH; c0 += 4) {
        // Warp-sample 4 channels x 4 positions into registers
        float fN[4][4];
        #pragma unroll
        for (int cc = 0; cc < 4; ++cc) {
            const float* f1c = f1b + (size_t)(c0 + cc) * ZYX;
            #pragma unroll
            for (int i = 0; i < 4; ++i) {
                float a = cw[i][0] * f1c[cidx[i][0]];
                a += cw[i][1] * f1c[cidx[i][1]];
                a += cw[i][2] * f1c[cidx[i][2]];
                a += cw[i][3] * f1c[cidx[i][3]];
                fN[cc][i] = a;
            }
        }
        // Correlate: acc[o] += sum_q featN[q] * feat0[q - o]
        #pragma unroll
        for (int cc = 0; cc < 4; ++cc) {
            const float* f0c = f0b + (size_t)(c0 + cc) * ZYX;
            #pragma unroll
            for (int oz = -1; oz <= 1; ++oz) {
                const int zz = z - oz;
                const bool zok = (unsigned)zz < 64u;
                #pragma unroll
                for (int oy = -1; oy <= 1; ++oy) {
                    const int yy = y - oy;
                    const bool rok = zok && ((unsigned)yy < 32u);
                    const float* rowp = f0c + (zz * YX + yy * XD);
                    float rr[6];
                    rr[0] = (rok && x0 > 0) ? rowp[x0 - 1] : 0.0f;
                    if (rok) {
                        const float4 v4 = *(const float4*)(rowp + x0);
                        rr[1] = v4.x; rr[2] = v4.y; rr[3] = v4.z; rr[4] = v4.w;
                    } else {
                        rr[1] = rr[2] = rr[3] = rr[4] = 0.0f;
                    }
                    rr[5] = (rok && x0 < 60) ? rowp[x0 + 4] : 0.0f;
                    #pragma unroll
                    for (int ox = -1; ox <= 1; ++ox) {
                        const int o = (oz + 1) * 9 + (oy + 1) * 3 + (ox + 1);
                        acc[o] += fN[cc][0] * rr[1 - ox] + fN[cc][1] * rr[2 - ox]
                                + fN[cc][2] * rr[3 - ox] + fN[cc][3] * rr[4 - ox];
                    }
                }
            }
        }
    }

    // Block reduction of acc[27] (fixed order -> deterministic)
    __shared__ float red[4][27];
    #pragma unroll 1
    for (int o = 0; o < 27; ++o) {
        float v = acc[o];
        #pragma unroll
        for (int d = 32; d >= 1; d >>= 1) v += __shfl_down(v, d, 64);
        if ((tid & 63) == 0) red[tid >> 6][o] = v;
    }
    __syncthreads();
    if (tid < 27) {
        float v = red[0][tid] + red[1][tid] + red[2][tid] + red[3][tid];
        partial[((size_t)n * NTILE + tile) * 27 + tid] = v;
    }
}

// ---------------------------------------------------------------------------
// Kernel 2: reduce partials -> heat, run per-batch MLP, emit loss + 4x4
// matrices (d_out[0..64]) and warp params for kernel 3 (in ws).
// Single block of 128 threads.
// ---------------------------------------------------------------------------
__global__ __launch_bounds__(128) void k_mlp(const float* __restrict__ partial,
                                             const float* __restrict__ camg,
                                             const float* __restrict__ W1,
                                             const float* __restrict__ b1,
                                             const float* __restrict__ W2,
                                             const float* __restrict__ b2,
                                             const float* __restrict__ W3,
                                             const float* __restrict__ b3,
                                             float* __restrict__ out,
                                             float* __restrict__ params)
{
    __shared__ float heat[324];
    __shared__ float f[81];
    __shared__ float h1[128];
    __shared__ float h2[128];
    __shared__ float denom_s;
    __shared__ float res[NB][8];
    const int tid = (int)threadIdx.x;

    for (int p = tid; p < 324; p += 128) {
        const int n = p / 27, o = p % 27;
        const float* pp = partial + (size_t)n * NTILE * 27 + o;
        float s = 0.0f;
        for (int t = 0; t < NTILE; ++t) s += pp[t * 27];
        heat[p] = s * INVC;
    }
    __syncthreads();

    for (int b = 0; b < NB; ++b) {
        if (tid < 81) {
            float v = heat[b * 81 + tid];
            f[tid] = (v >= 0.0f) ? v : 0.1f * v;
        }
        __syncthreads();
        if (tid == 0) {
            float ss = 0.0f;
            for (int k = 0; k < 81; ++k) ss += f[k] * f[k];
            denom_s = 1e-6f + sqrtf(ss);
        }
        __syncthreads();
        if (tid < 81) f[tid] = f[tid] / denom_s;
        __syncthreads();
        {
            float a = b1[tid];
            const float* wr = W1 + tid * 81;
            for (int k = 0; k < 81; ++k) a += wr[k] * f[k];
            h1[tid] = (a >= 0.0f) ? a : 0.1f * a;
        }
        __syncthreads();
        {
            float a = b2[tid];
            const float* wr = W2 + tid * 128;
            for (int k = 0; k < 128; ++k) a += wr[k] * h1[k];
            h2[tid] = (a >= 0.0f) ? a : 0.1f * a;
        }
        __syncthreads();
        if (tid < 4) {
            float a = b3[tid];
            const float* wr = W3 + tid * 128;
            for (int k = 0; k < 128; ++k) a += wr[k] * h2[k];
            res[b][4 + tid] = a;
        }
        __syncthreads();
        if (tid == 0) {
            const float r_out = res[b][4], yv = res[b][5], xv = res[b][6], zv = res[b][7];
            const float th = r_out * D2R;
            const float c2 = cosf(th), s2 = sinf(th);
            float* m = out + 1 + b * 16;
            m[0] = c2;  m[1] = 0.0f; m[2] = s2;  m[3] = -xv;
            m[4] = 0.0f; m[5] = 1.0f; m[6] = 0.0f; m[7] = -yv;
            m[8] = -s2; m[9] = 0.0f; m[10] = c2; m[11] = -zv;
            m[12] = 0.0f; m[13] = 0.0f; m[14] = 0.0f; m[15] = 1.0f;
            // Inverse-transform params for sampling: R^T, t' = R^T * delta
            params[b * 8 + 0] = c2;
            params[b * 8 + 1] = s2;
            params[b * 8 + 2] = c2 * xv - s2 * zv;
            params[b * 8 + 3] = yv;
            params[b * 8 + 4] = s2 * xv + c2 * zv;
            res[b][0] = -xv; res[b][1] = -yv; res[b][2] = -zv;
            res[b][3] = atan2f(s2, c2) * R2D;
        }
        __syncthreads();
    }

    if (tid == 0) {
        float tl2 = 0.0f, dl2 = 0.0f;
        for (int b = 0; b < NB; ++b) {
            const float* g = camg + b * 16;
            const float dx = res[b][0] - g[3];
            const float dy = res[b][1] - g[7];
            const float dz = res[b][2] - g[11];
            tl2 += dx * dx + dy * dy + dz * dz;
            const float dg = atan2f(g[2], g[10]) * R2D;
            const float dd = res[b][3] - dg;
            dl2 += dd * dd;
        }
        out[0] = tl2 * 0.25f + dl2 * 0.25f;
    }
}

// ---------------------------------------------------------------------------
// Kernel 3: warp feat1 by estimated transform -> feat1_warped (d_out + 65).
// Full trilinear (translation has a y-component).
// ---------------------------------------------------------------------------
__global__ __launch_bounds__(256) void k_warp(const float* __restrict__ feat1,
                                              const float* __restrict__ params,
                                              float* __restrict__ outw)
{
    const int b = blockIdx.y;
    const int p = (int)blockIdx.x * 256 + (int)threadIdx.x;  // 0..131071
    const int z = p >> 11;
    const int y = (p >> 6) & 31;
    const int x = p & 63;

    const float cs = params[b * 8 + 0], sn = params[b * 8 + 1];
    const float tpx = params[b * 8 + 2], tpy = params[b * 8 + 3], tpz = params[b * 8 + 4];

    const float rx = (float)x - 31.5f;
    const float ry = (float)y - 15.5f;
    const float rz = (float)z - 31.5f;
    const float sx = cs * rx - sn * rz + tpx + 31.5f;
    const float sy = ry + tpy + 15.5f;
    const float sz = sn * rx + cs * rz + tpz + 31.5f;

    const float xf = floorf(sx), yf = floorf(sy), zf = floorf(sz);
    const float fx = sx - xf, fy = sy - yf, fz = sz - zf;
    const int ix = (int)xf, iy = (int)yf, iz = (int)zf;

    const float wx[2] = {1.0f - fx, fx};
    const float wy[2] = {1.0f - fy, fy};
    const float wz[2] = {1.0f - fz, fz};
    const int xs[2] = {min(max(ix, 0), 63), min(max(ix + 1, 0), 63)};
    const int ys[2] = {min(max(iy, 0), 31), min(max(iy + 1, 0), 31)};
    const int zs[2] = {min(max(iz, 0), 63), min(max(iz + 1, 0), 63)};
    const bool vx[2] = {(unsigned)ix < 64u, (unsigned)(ix + 1) < 64u};
    const bool vy[2] = {(unsigned)iy < 32u, (unsigned)(iy + 1) < 32u};
    const bool vz[2] = {(unsigned)iz < 64u, (unsigned)(iz + 1) < 64u};

    int idx[8]; float w[8];
    int q = 0;
    #pragma unroll
    for (int dz = 0; dz < 2; ++dz)
        #pragma unroll
        for (int dy = 0; dy < 2; ++dy)
            #pragma unroll
            for (int dx = 0; dx < 2; ++dx) {
                idx[q] = zs[dz] * YX + ys[dy] * XD + xs[dx];
                w[q] = (vx[dx] && vy[dy] && vz[dz]) ? wx[dx] * wy[dy] * wz[dz] : 0.0f;
                ++q;
            }

    const float* f1b = feat1 + (size_t)b * NCH * ZYX;
    float* ob = outw + (size_t)b * NCH * ZYX;
    #pragma unroll 1
    for (int c = 0; c < NCH; ++c) {
        const float* f1c = f1b + (size_t)c * ZYX;
        float a = 0.0f;
        #pragma unroll
        for (int k = 0; k < 8; ++k) a += w[k] * f1c[idx[k]];
        ob[(size_t)c * ZYX + p] = a;
    }
}

// ---------------------------------------------------------------------------
extern "C" void kernel_launch(void* const* d_in, const int* in_sizes, int n_in,
                              void* d_out, int out_size, void* d_ws, size_t ws_size,
                              hipStream_t stream)
{
    (void)in_sizes; (void)n_in; (void)out_size; (void)ws_size;
    const float* feat0 = (const float*)d_in[0];
    const float* feat1 = (const float*)d_in[1];
    const float* camg  = (const float*)d_in[2];
    const float* W1 = (const float*)d_in[3];
    const float* b1 = (const float*)d_in[4];
    const float* W2 = (const float*)d_in[5];
    const float* b2 = (const float*)d_in[6];
    const float* W3 = (const float*)d_in[7];
    const float* b3 = (const float*)d_in[8];
    float* out = (float*)d_out;

    float* partial = (float*)d_ws;                 // 12*128*27 floats = 166 KB
    float* params  = partial + 12 * NTILE * 27;    // 32 floats

    dim3 g1(NTILE, 12);
    hipLaunchKernelGGL(k_heat, g1, dim3(256), 0, stream, feat0, feat1, partial);
    hipLaunchKernelGGL(k_mlp, dim3(1), dim3(128), 0, stream,
                       partial, camg, W1, b1, W2, b2, W3, b3, out, params);
    dim3 g3(ZYX / 256, NB);
    hipLaunchKernelGGL(k_warp, g3, dim3(256), 0, stream, feat1, params, out + 65);
}

// Round 3
// 375.817 us; speedup vs baseline: 2.0571x; 2.0571x over previous
//
#include <hip/hip_runtime.h>
#include <math.h>

#define NCH 32
#define ZYX (64*32*64)
#define NB 4
#define NT 64               // z-tiles(8) * y-tiles(8) per n
#define INVC (1.0f/(32.0f+1e-6f))
#define D2R 0.017453292519943295f
#define R2D 57.29577951308232f

// LDS slab geometry (pitch 68 floats: +4 pad columns, zeroed -> free x-edge handling
// and bank spread: 68 % 32 = 4 shifts banks per row)
#define P0 68
#define F0SZ 4096           // padded chunks (real 4080 = 10z*6y*68)
#define F1SZ 3840           // padded chunks (real 3808 = 14z*4y*68)
#define F0B 4               // feat0 slab starts at L[4]; L[0..3] zero guard
#define F1B (4 + F0SZ)

// ---------------------------------------------------------------------------
// Kernel 1: fused rotate-warp(feat1) x 27-offset correlation vs feat0,
// LDS-staged per channel, spatially reduced -> partial[n][tile][27].
// Block tile: 8z x 4y x 64x. Thread owns 2 contiguous z x 4 x (8 positions).
// ---------------------------------------------------------------------------
__global__ __launch_bounds__(256, 3) void k_heat(const float* __restrict__ feat0,
                                                 const float* __restrict__ feat1,
                                                 float* __restrict__ partial)
{
    __shared__ float L[4 + F0SZ + F1SZ];
    __shared__ float red[4][27];

    const int n = blockIdx.y;            // 0..11 (b*3 + r)
    const int tileid = blockIdx.x;       // 0..63
    const int zt = tileid >> 3, yt = tileid & 7;
    const int b = n / 3, r = n - 3 * b;
    const int tid = (int)threadIdx.x;
    const int tx = tid & 15, ty = (tid >> 4) & 3, wv = tid >> 6;
    const int lane = tid & 63;

    const int z0 = 8 * zt + 2 * wv;      // owns z0, z0+1
    const int x0 = 4 * tx;

    if (tid < 4) L[tid] = 0.0f;          // zero guard (x=-1 of first row)

    const float th = (-4.0f + 4.0f * (float)r) * D2R;
    const float cs = cosf(th), sn = sinf(th);

    // ---- bilinear sample setup (channel-invariant) ----
    float WX0[2][4], WX1[2][4], WZ0[2][4], WZ1[2][4];
    int   A1[2][4];
    #pragma unroll
    for (int j = 0; j < 2; ++j) {
        #pragma unroll
        for (int i = 0; i < 4; ++i) {
            const float rx = (float)(x0 + i) - 31.5f;
            const float rz = (float)(z0 + j) - 31.5f;
            const float sx = cs * rx - sn * rz + 31.5f;
            const float sz = sn * rx + cs * rz + 31.5f;
            const float xf = floorf(sx), zf = floorf(sz);
            const float fx = sx - xf, fz = sz - zf;
            const int ix = (int)xf, iz = (int)zf;
            WX0[j][i] = ((unsigned)ix < 64u) ? (1.0f - fx) : 0.0f;
            WX1[j][i] = ((unsigned)(ix + 1) < 64u) ? fx : 0.0f;
            WZ0[j][i] = 1.0f - fz;       // z OOB rows are staged as zeros
            WZ1[j][i] = fz;
            int zl = iz - (8 * zt - 3);
            zl = min(max(zl, 0), 12);
            const int bx = min(max(ix, -1), 63);
            A1[j][i] = F1B + (zl * 4 + ty) * P0 + bx;
        }
    }

    // ---- staging setup: 31 chunks of 256 floats (16 feat0 + 15 feat1) ----
    // wave w takes chunks c = w + 4k; k<4 -> feat0, k>=4 -> feat1.
    // Masked-out lanes load from offset 0 (aligned, in-bounds) and are zeroed.
    int goff[8]; float gmask[8];
    const int nck = (wv == 3) ? 7 : 8;
    #pragma unroll
    for (int k = 0; k < 8; ++k) {
        const int c = wv + 4 * k;
        int zs, ys, x, ok;
        if (k < 4) {                      // feat0 slab [10][6][68]
            const int q = c * 256 + lane * 4;
            const int zr = q / 408, rem = q - zr * 408;
            const int yr = rem / 68; x = rem - yr * 68;
            zs = 8 * zt - 1 + zr; ys = 4 * yt - 1 + yr;
            ok = (q < 4080) & (x < 64) & (zs >= 0) & (zs < 64) & (ys >= 0) & (ys < 32);
        } else {                          // feat1 slab [14][4][68]
            const int q = c * 256 + lane * 4 - 4096;
            const int zr = q / 272, rem = q - zr * 272;
            const int yr = rem / 68; x = rem - yr * 68;
            zs = 8 * zt - 3 + zr; ys = 4 * yt + yr;
            ok = (q < 3808) & (x < 64) & (zs >= 0) & (zs < 64);
        }
        goff[k] = ok ? (zs * 2048 + ys * 64 + x) : 0;
        gmask[k] = ok ? 1.0f : 0.0f;
    }

    const float* f0b_ = feat0 + (size_t)b * NCH * ZYX;
    const float* f1b_ = feat1 + (size_t)b * NCH * ZYX;
    const int rw = F0B + (2 * wv * 6 + ty) * P0 + x0;   // corr row base (this thread)

    float acc[27];
    #pragma unroll
    for (int o = 0; o < 27; ++o) acc[o] = 0.0f;

    float4 vv[8];
    // prologue: loads for channel 0
    #pragma unroll
    for (int k = 0; k < 8; ++k) if (k < nck)
        vv[k] = *(const float4*)(((k < 4) ? f0b_ : f1b_) + goff[k]);

    #pragma unroll 1
    for (int ch = 0; ch < NCH; ++ch) {
        // ---- write staged data (mask junk/OOB/pad to exact zeros) ----
        #pragma unroll
        for (int k = 0; k < 8; ++k) if (k < nck) {
            float4 v = vv[k]; const float mq = gmask[k];
            v.x *= mq; v.y *= mq; v.z *= mq; v.w *= mq;
            const int c = wv + 4 * k;
            *(float4*)&L[4 + c * 256 + lane * 4] = v;
        }
        __syncthreads();

        // ---- T14: issue next channel's global loads before compute ----
        if (ch + 1 < NCH) {
            const float* f0c = f0b_ + (size_t)(ch + 1) * ZYX;
            const float* f1c = f1b_ + (size_t)(ch + 1) * ZYX;
            #pragma unroll
            for (int k = 0; k < 8; ++k) if (k < nck)
                vv[k] = *(const float4*)(((k < 4) ? f0c : f1c) + goff[k]);
        }

        // ---- bilinear warp-sample: 8 positions from LDS ----
        float fa[4], fb[4];
        #pragma unroll
        for (int j = 0; j < 2; ++j) {
            #pragma unroll
            for (int i = 0; i < 4; ++i) {
                const int a = A1[j][i];
                const float p0x = L[a], p0y = L[a + 1];
                const float p1x = L[a + 4 * P0], p1y = L[a + 4 * P0 + 1];
                const float t = WZ0[j][i] * p0x + WZ1[j][i] * p1x;
                const float u = WZ0[j][i] * p0y + WZ1[j][i] * p1y;
                const float v_ = WX0[j][i] * t + WX1[j][i] * u;
                if (j == 0) fa[i] = v_; else fb[i] = v_;
            }
        }

        // ---- correlation: 12 rows serve both owned z, all 27 offsets ----
        #pragma unroll
        for (int yri = 0; yri < 3; ++yri) {
            #pragma unroll
            for (int zri = 0; zri < 4; ++zri) {
                const int off = zri * 408 + yri * 68;
                const float4 m4 = *(const float4*)&L[rw + off];
                const float e0 = L[rw + off - 1];
                const float e1 = L[rw + off + 4];
                const int oy1 = 2 - yri;
                if (zri <= 2) {           // contributes for z0 (oz+1 = 2-zri)
                    const int ob = (2 - zri) * 9 + oy1 * 3;
                    acc[ob + 0] += fa[0] * m4.y + fa[1] * m4.z + fa[2] * m4.w + fa[3] * e1;
                    acc[ob + 1] += fa[0] * m4.x + fa[1] * m4.y + fa[2] * m4.z + fa[3] * m4.w;
                    acc[ob + 2] += fa[0] * e0   + fa[1] * m4.x + fa[2] * m4.y + fa[3] * m4.z;
                }
                if (zri >= 1) {           // contributes for z0+1 (oz+1 = 3-zri)
                    const int ob = (3 - zri) * 9 + oy1 * 3;
                    acc[ob + 0] += fb[0] * m4.y + fb[1] * m4.z + fb[2] * m4.w + fb[3] * e1;
                    acc[ob + 1] += fb[0] * m4.x + fb[1] * m4.y + fb[2] * m4.z + fb[3] * m4.w;
                    acc[ob + 2] += fb[0] * e0   + fb[1] * m4.x + fb[2] * m4.y + fb[3] * m4.z;
                }
            }
        }
        __syncthreads();
    }

    // ---- block reduction (fixed order -> deterministic) ----
    #pragma unroll 1
    for (int o = 0; o < 27; ++o) {
        float v = acc[o];
        #pragma unroll
        for (int d = 32; d >= 1; d >>= 1) v += __shfl_down(v, d, 64);
        if (lane == 0) red[wv][o] = v;
    }
    __syncthreads();
    if (tid < 27) {
        const float v = red[0][tid] + red[1][tid] + red[2][tid] + red[3][tid];
        partial[((size_t)n * NT + tileid) * 27 + tid] = v;
    }
}

// ---------------------------------------------------------------------------
// Kernel 2: reduce partials -> heat, per-batch MLP, loss + matrices + params.
// ---------------------------------------------------------------------------
__global__ __launch_bounds__(128) void k_mlp(const float* __restrict__ partial,
                                             const float* __restrict__ camg,
                                             const float* __restrict__ W1,
                                             const float* __restrict__ b1,
                                             const float* __restrict__ W2,
                                             const float* __restrict__ b2,
                                             const float* __restrict__ W3,
                                             const float* __restrict__ b3,
                                             float* __restrict__ out,
                                             float* __restrict__ params)
{
    __shared__ float heat[324];
    __shared__ float f[81];
    __shared__ float h1[128];
    __shared__ float h2[128];
    __shared__ float denom_s;
    __shared__ float res[NB][8];
    const int tid = (int)threadIdx.x;

    for (int p = tid; p < 324; p += 128) {
        const int n = p / 27, o = p % 27;
        const float* pp = partial + (size_t)n * NT * 27 + o;
        float s = 0.0f;
        for (int t = 0; t < NT; ++t) s += pp[t * 27];
        heat[p] = s * INVC;
    }
    __syncthreads();

    for (int b = 0; b < NB; ++b) {
        if (tid < 81) {
            float v = heat[b * 81 + tid];
            f[tid] = (v >= 0.0f) ? v : 0.1f * v;
        }
        __syncthreads();
        if (tid == 0) {
            float ss = 0.0f;
            for (int k = 0; k < 81; ++k) ss += f[k] * f[k];
            denom_s = 1e-6f + sqrtf(ss);
        }
        __syncthreads();
        if (tid < 81) f[tid] = f[tid] / denom_s;
        __syncthreads();
        {
            float a = b1[tid];
            const float* wr = W1 + tid * 81;
            for (int k = 0; k < 81; ++k) a += wr[k] * f[k];
            h1[tid] = (a >= 0.0f) ? a : 0.1f * a;
        }
        __syncthreads();
        {
            float a = b2[tid];
            const float* wr = W2 + tid * 128;
            for (int k = 0; k < 128; ++k) a += wr[k] * h1[k];
            h2[tid] = (a >= 0.0f) ? a : 0.1f * a;
        }
        __syncthreads();
        if (tid < 4) {
            float a = b3[tid];
            const float* wr = W3 + tid * 128;
            for (int k = 0; k < 128; ++k) a += wr[k] * h2[k];
            res[b][4 + tid] = a;
        }
        __syncthreads();
        if (tid == 0) {
            const float r_out = res[b][4], yv = res[b][5], xv = res[b][6], zv = res[b][7];
            const float t2 = r_out * D2R;
            const float c2 = cosf(t2), s2 = sinf(t2);
            float* m = out + 1 + b * 16;
            m[0] = c2;  m[1] = 0.0f; m[2] = s2;  m[3] = -xv;
            m[4] = 0.0f; m[5] = 1.0f; m[6] = 0.0f; m[7] = -yv;
            m[8] = -s2; m[9] = 0.0f; m[10] = c2; m[11] = -zv;
            m[12] = 0.0f; m[13] = 0.0f; m[14] = 0.0f; m[15] = 1.0f;
            params[b * 8 + 0] = c2;
            params[b * 8 + 1] = s2;
            params[b * 8 + 2] = c2 * xv - s2 * zv;
            params[b * 8 + 3] = yv;
            params[b * 8 + 4] = s2 * xv + c2 * zv;
            res[b][0] = -xv; res[b][1] = -yv; res[b][2] = -zv;
            res[b][3] = atan2f(s2, c2) * R2D;
        }
        __syncthreads();
    }

    if (tid == 0) {
        float tl2 = 0.0f, dl2 = 0.0f;
        for (int b = 0; b < NB; ++b) {
            const float* g = camg + b * 16;
            const float dx = res[b][0] - g[3];
            const float dy = res[b][1] - g[7];
            const float dz = res[b][2] - g[11];
            tl2 += dx * dx + dy * dy + dz * dz;
            const float dg = atan2f(g[2], g[10]) * R2D;
            const float dd = res[b][3] - dg;
            dl2 += dd * dd;
        }
        out[0] = tl2 * 0.25f + dl2 * 0.25f;
    }
}

// ---------------------------------------------------------------------------
// Kernel 3: warp feat1 by estimated transform -> feat1_warped (d_out + 65).
// ---------------------------------------------------------------------------
__global__ __launch_bounds__(256) void k_warp(const float* __restrict__ feat1,
                                              const float* __restrict__ params,
                                              float* __restrict__ outw)
{
    const int b = blockIdx.y;
    const int p = (int)blockIdx.x * 256 + (int)threadIdx.x;
    const int z = p >> 11;
    const int y = (p >> 6) & 31;
    const int x = p & 63;

    const float cs = params[b * 8 + 0], sn = params[b * 8 + 1];
    const float tpx = params[b * 8 + 2], tpy = params[b * 8 + 3], tpz = params[b * 8 + 4];

    const float rx = (float)x - 31.5f;
    const float ry = (float)y - 15.5f;
    const float rz = (float)z - 31.5f;
    const float sx = cs * rx - sn * rz + tpx + 31.5f;
    const float sy = ry + tpy + 15.5f;
    const float sz = sn * rx + cs * rz + tpz + 31.5f;

    const float xf = floorf(sx), yf = floorf(sy), zf = floorf(sz);
    const float fx = sx - xf, fy = sy - yf, fz = sz - zf;
    const int ix = (int)xf, iy = (int)yf, iz = (int)zf;

    const float wx[2] = {1.0f - fx, fx};
    const float wy[2] = {1.0f - fy, fy};
    const float wz[2] = {1.0f - fz, fz};
    const int xs[2] = {min(max(ix, 0), 63), min(max(ix + 1, 0), 63)};
    const int ys[2] = {min(max(iy, 0), 31), min(max(iy + 1, 0), 31)};
    const int zs[2] = {min(max(iz, 0), 63), min(max(iz + 1, 0), 63)};
    const bool vx[2] = {(unsigned)ix < 64u, (unsigned)(ix + 1) < 64u};
    const bool vy[2] = {(unsigned)iy < 32u, (unsigned)(iy + 1) < 32u};
    const bool vz[2] = {(unsigned)iz < 64u, (unsigned)(iz + 1) < 64u};

    int idx[8]; float w[8];
    int q = 0;
    #pragma unroll
    for (int dz = 0; dz < 2; ++dz)
        #pragma unroll
        for (int dy = 0; dy < 2; ++dy)
            #pragma unroll
            for (int dx = 0; dx < 2; ++dx) {
                idx[q] = zs[dz] * 2048 + ys[dy] * 64 + xs[dx];
                w[q] = (vx[dx] && vy[dy] && vz[dz]) ? wx[dx] * wy[dy] * wz[dz] : 0.0f;
                ++q;
            }

    const float* f1b = feat1 + (size_t)b * NCH * ZYX;
    float* ob = outw + (size_t)b * NCH * ZYX;
    #pragma unroll 1
    for (int c = 0; c < NCH; ++c) {
        const float* f1c = f1b + (size_t)c * ZYX;
        float a = 0.0f;
        #pragma unroll
        for (int k = 0; k < 8; ++k) a += w[k] * f1c[idx[k]];
        ob[(size_t)c * ZYX + p] = a;
    }
}

// ---------------------------------------------------------------------------
extern "C" void kernel_launch(void* const* d_in, const int* in_sizes, int n_in,
                              void* d_out, int out_size, void* d_ws, size_t ws_size,
                              hipStream_t stream)
{
    (void)in_sizes; (void)n_in; (void)out_size; (void)ws_size;
    const float* feat0 = (const float*)d_in[0];
    const float* feat1 = (const float*)d_in[1];
    const float* camg  = (const float*)d_in[2];
    const float* W1 = (const float*)d_in[3];
    const float* b1 = (const float*)d_in[4];
    const float* W2 = (const float*)d_in[5];
    const float* b2 = (const float*)d_in[6];
    const float* W3 = (const float*)d_in[7];
    const float* b3 = (const float*)d_in[8];
    float* out = (float*)d_out;

    float* partial = (float*)d_ws;                 // 12*64*27 floats ~ 83 KB
    float* params  = partial + 12 * NT * 27;       // 32 floats

    dim3 g1(NT, 12);
    hipLaunchKernelGGL(k_heat, g1, dim3(256), 0, stream, feat0, feat1, partial);
    hipLaunchKernelGGL(k_mlp, dim3(1), dim3(128), 0, stream,
                       partial, camg, W1, b1, W2, b2, W3, b3, out, params);
    dim3 g3(ZYX / 256, NB);
    hipLaunchKernelGGL(k_warp, g3, dim3(256), 0, stream, feat1, params, out + 65);
}